// Round 14
// baseline (3949.221 us; speedup 1.0000x reference)
//
#include <hip/hip_runtime.h>

typedef unsigned int u32;
typedef unsigned short u16;
typedef unsigned long long u64;
typedef float f32x4 __attribute__((ext_vector_type(4)));
typedef _Float16 f16x8 __attribute__((ext_vector_type(8)));
typedef u32 u32x4 __attribute__((ext_vector_type(4)));

#define S_LEN 1024
#define NG 8      // groups = XCDs (dynamic mode) or bid&7 (fallback)
#define NM 32     // member blocks per group
#define GBAT 16   // batches per group
#define PSTR 20   // pred col stride (floats)

__device__ __forceinline__ u16 f2h_bits(float f) {
  _Float16 h = (_Float16)f;
  return __builtin_bit_cast(u16, h);
}
__device__ __forceinline__ float h2f_bits(u16 b) {
  return (float)__builtin_bit_cast(_Float16, b);
}
__device__ __forceinline__ u32 pk2(float a, float b) {
  return (u32)f2h_bits(a) | ((u32)f2h_bits(b) << 16);
}
__device__ __forceinline__ u32 pkh(u64 v) {
  return (u32)(v & 0xFFFFu) | (((u32)(v >> 32) & 0xFFFFu) << 16);
}

// Pre-arrange W into MFMA fragment-major order, fp16 (layout verified r2-r11);
// blk 0 zeroes the roster (16 words) -> graph-replay safe.
__global__ __launch_bounds__(256) void prep_frags(const float* __restrict__ Wi,
                                                  const float* __restrict__ Wh,
                                                  uint4* __restrict__ wf4,
                                                  u32* __restrict__ roster) {
  const int blk = blockIdx.x;               // 0..63
  if (blk == 0 && threadIdx.x < 16) roster[threadIdx.x] = 0;
  const int m = blk & 31;
  const float* __restrict__ W = (blk & 32) ? Wh : Wi;
  uint4* __restrict__ dst = wf4 + ((blk & 32) ? 131072 : 0) + m * 4096;
  for (int fi = threadIdx.x; fi < 4096; fi += 256) {
    const int lane = fi & 63;
    const int kc = (fi >> 6) & 15;
    const int q = fi >> 10;
    const int gq = lane >> 4, c = lane & 15;
    const int kb = kc * 32 + gq * 8;
    const int gcol = q * 512 + m * 16 + c;
    u32 wds[4];
#pragma unroll
    for (int pp = 0; pp < 4; ++pp) {
      u16 e0 = f2h_bits(W[(size_t)(kb + 2 * pp) * 2048 + gcol]);
      u16 e1 = f2h_bits(W[(size_t)(kb + 2 * pp + 1) * 2048 + gcol]);
      wds[pp] = (u32)e0 | ((u32)e1 << 16);
    }
    uint4 v; v.x = wds[0]; v.y = wds[1]; v.z = wds[2]; v.w = wds[3];
    dst[fi] = v;    // fi == (q*16+kc)*64+lane
  }
}

// Persistent LSTM, tagged-word protocol (word = (seq16<<16)|f16(h)).
// r11 (verbatim resubmit): groups formed DYNAMICALLY from physical XCD
// placement. 148KB LDS forces 1 block/CU; cooperative launch -> all 256
// resident -> exactly 32 blocks/XCD. Each block claims slot in
// roster[XCC_ID]; group = own XCD. Exchange stays on-die: plain stores land
// dirty in the XCD-shared write-back L2; polls use sc0 loads (bypass stale
// L1, hit same L2). If roster malformed (checked, uniform), ALL blocks fall
// back to static grouping + LLC sc1-atomic protocol (proven r6).
__global__ __launch_bounds__(256) void lstm_main(
    const float* __restrict__ x,
    const uint4* __restrict__ wif4,
    u32* __restrict__ hbuf,
    u32* __restrict__ roster,
    const float* __restrict__ bvec,
    const float* __restrict__ Wd,
    const float* __restrict__ bd,
    float* __restrict__ out) {
  __shared__ __align__(16) uint4 sWi[4096];
  __shared__ __align__(16) uint4 sWh[4096];
  __shared__ __align__(16) float pred[16][PSTR * 16];
  __shared__ u32 sMode, sG, sM;

  const int tid = threadIdx.x;
  const int lane = tid & 63;
  const int wv = tid >> 6;

  // ---- dynamic group formation (once)
  if (tid == 0) {
    u32 myxcc;
    asm volatile("s_getreg_b32 %0, hwreg(HW_REG_XCC_ID)" : "=s"(myxcc));
    const u32 x8 = myxcc & 7u;
    const u32 slot = __hip_atomic_fetch_add(roster + x8, 1u, __ATOMIC_RELAXED,
                                            __HIP_MEMORY_SCOPE_AGENT);
    __hip_atomic_fetch_add(roster + 8, 1u, __ATOMIC_RELAXED, __HIP_MEMORY_SCOPE_AGENT);
    while (__hip_atomic_load(roster + 8, __ATOMIC_RELAXED, __HIP_MEMORY_SCOPE_AGENT) < 256u)
      __builtin_amdgcn_s_sleep(1);
    u32 ok = (slot < 32u) ? 1u : 0u;
    for (int k = 0; k < 8; ++k)
      ok &= (__hip_atomic_load(roster + k, __ATOMIC_RELAXED,
                               __HIP_MEMORY_SCOPE_AGENT) == 32u) ? 1u : 0u;
    sMode = ok; sG = x8; sM = slot;
  }
  __syncthreads();
  const bool fastm = (sMode != 0u);
  const int g = fastm ? (int)sG : ((int)blockIdx.x & 7);
  const int m = fastm ? (int)sM : ((int)blockIdx.x >> 3);

  for (int i = tid; i < 4096; i += 256) {
    sWi[i] = wif4[m * 4096 + i];
    sWh[i] = wif4[131072 + m * 4096 + i];
  }

  const int bt = tid >> 4;          // batch within group (output row)
  const int hi_ = tid & 15;         // h-index within member slice (output col)
  const int gb = g * GBAT + bt;
  const int hidx = m * 16 + hi_;

  const float bi = bvec[hidx];
  const float bf_ = bvec[512 + hidx];
  const float bg = bvec[1024 + hidx];
  const float bo = bvec[1536 + hidx];
  float c_reg = 0.f;

  // per-lane A-fragment source coordinates (verified r2-r11)
  const int abt = lane & 15;        // batch row this lane supplies
  const int oct = lane >> 4;        // k-octet within kc
  const float* __restrict__ xrow = x + (size_t)(g * GBAT + abt) * (S_LEN * 512);
  const u32 hrow_off = ((u32)(g * GBAT + abt)) << 9;

  __syncthreads();   // weights ready

  float4 xa[8], xb[8];
#pragma unroll
  for (int kk = 0; kk < 4; ++kk) {
    const int k0 = ((wv << 2) | kk) * 32 + oct * 8;
    xa[2 * kk]     = *reinterpret_cast<const float4*>(xrow + k0);
    xa[2 * kk + 1] = *reinterpret_cast<const float4*>(xrow + k0 + 4);
  }

  auto step = [&](int t, float4* cur, float4* nxt) {
    // ---- issue x(t+1) prefetch
    {
      int tn = t + 1; tn = (tn < S_LEN) ? tn : (S_LEN - 1);
      const float* xr = xrow + (size_t)tn * 512;
#pragma unroll
      for (int kk = 0; kk < 4; ++kk) {
        const int k0 = ((wv << 2) | kk) * 32 + oct * 8;
        nxt[2 * kk]     = *reinterpret_cast<const float4*>(xr + k0);
        nxt[2 * kk + 1] = *reinterpret_cast<const float4*>(xr + k0 + 4);
      }
    }

    // ---- x(t) @ Wi from prefetched regs
    f32x4 acc0 = {0.f, 0.f, 0.f, 0.f}, acc1 = acc0, acc2 = acc0, acc3 = acc0;
#pragma unroll
    for (int kk = 0; kk < 4; ++kk) {
      const int kc = (wv << 2) | kk;
      uint4 av;
      av.x = pk2(cur[2 * kk].x, cur[2 * kk].y);
      av.y = pk2(cur[2 * kk].z, cur[2 * kk].w);
      av.z = pk2(cur[2 * kk + 1].x, cur[2 * kk + 1].y);
      av.w = pk2(cur[2 * kk + 1].z, cur[2 * kk + 1].w);
      f16x8 af = __builtin_bit_cast(f16x8, av);
      acc0 = __builtin_amdgcn_mfma_f32_16x16x32_f16(af, __builtin_bit_cast(f16x8, sWi[(0 * 16 + kc) * 64 + lane]), acc0, 0, 0, 0);
      acc1 = __builtin_amdgcn_mfma_f32_16x16x32_f16(af, __builtin_bit_cast(f16x8, sWi[(1 * 16 + kc) * 64 + lane]), acc1, 0, 0, 0);
      acc2 = __builtin_amdgcn_mfma_f32_16x16x32_f16(af, __builtin_bit_cast(f16x8, sWi[(2 * 16 + kc) * 64 + lane]), acc2, 0, 0, 0);
      acc3 = __builtin_amdgcn_mfma_f32_16x16x32_f16(af, __builtin_bit_cast(f16x8, sWi[(3 * 16 + kc) * 64 + lane]), acc3, 0, 0, 0);
    }

    if (t > 0) {
      const u32 tg = (u32)t << 16;
      uint4 hv[4];

      if (fastm) {
        // ---- FAST: poll own-XCD L2 with sc0 loads
        const u32* p2 = hbuf + (((u32)(t & 1)) << 16) + hrow_off +
                        ((u32)((wv << 7) | (oct << 3)));
        for (;;) {
          u32x4 fA0, fB0, fA1, fB1, fA2, fB2, fA3, fB3;
          asm volatile("global_load_dwordx4 %0, %1, off sc0" : "=&v"(fA0) : "v"(p2));
          asm volatile("global_load_dwordx4 %0, %1, off offset:16 sc0" : "=&v"(fB0) : "v"(p2));
          asm volatile("global_load_dwordx4 %0, %1, off offset:128 sc0" : "=&v"(fA1) : "v"(p2));
          asm volatile("global_load_dwordx4 %0, %1, off offset:144 sc0" : "=&v"(fB1) : "v"(p2));
          asm volatile("global_load_dwordx4 %0, %1, off offset:256 sc0" : "=&v"(fA2) : "v"(p2));
          asm volatile("global_load_dwordx4 %0, %1, off offset:272 sc0" : "=&v"(fB2) : "v"(p2));
          asm volatile("global_load_dwordx4 %0, %1, off offset:384 sc0" : "=&v"(fA3) : "v"(p2));
          asm volatile("global_load_dwordx4 %0, %1, off offset:400 sc0" : "=&v"(fB3) : "v"(p2));
          asm volatile("s_waitcnt vmcnt(0)" ::: "memory");
          __builtin_amdgcn_sched_barrier(0);
          u32 bad = (fA0.x ^ tg) | (fA0.y ^ tg) | (fA0.z ^ tg) | (fA0.w ^ tg);
          bad |= (fB0.x ^ tg) | (fB0.y ^ tg) | (fB0.z ^ tg) | (fB0.w ^ tg);
          bad |= (fA1.x ^ tg) | (fA1.y ^ tg) | (fA1.z ^ tg) | (fA1.w ^ tg);
          bad |= (fB1.x ^ tg) | (fB1.y ^ tg) | (fB1.z ^ tg) | (fB1.w ^ tg);
          bad |= (fA2.x ^ tg) | (fA2.y ^ tg) | (fA2.z ^ tg) | (fA2.w ^ tg);
          bad |= (fB2.x ^ tg) | (fB2.y ^ tg) | (fB2.z ^ tg) | (fB2.w ^ tg);
          bad |= (fA3.x ^ tg) | (fA3.y ^ tg) | (fA3.z ^ tg) | (fA3.w ^ tg);
          bad |= (fB3.x ^ tg) | (fB3.y ^ tg) | (fB3.z ^ tg) | (fB3.w ^ tg);
          if (__all((bad & 0xFFFF0000u) == 0u)) {
            hv[0].x = (fA0.x & 0xFFFFu) | (fA0.y << 16); hv[0].y = (fA0.z & 0xFFFFu) | (fA0.w << 16);
            hv[0].z = (fB0.x & 0xFFFFu) | (fB0.y << 16); hv[0].w = (fB0.z & 0xFFFFu) | (fB0.w << 16);
            hv[1].x = (fA1.x & 0xFFFFu) | (fA1.y << 16); hv[1].y = (fA1.z & 0xFFFFu) | (fA1.w << 16);
            hv[1].z = (fB1.x & 0xFFFFu) | (fB1.y << 16); hv[1].w = (fB1.z & 0xFFFFu) | (fB1.w << 16);
            hv[2].x = (fA2.x & 0xFFFFu) | (fA2.y << 16); hv[2].y = (fA2.z & 0xFFFFu) | (fA2.w << 16);
            hv[2].z = (fB2.x & 0xFFFFu) | (fB2.y << 16); hv[2].w = (fB2.z & 0xFFFFu) | (fB2.w << 16);
            hv[3].x = (fA3.x & 0xFFFFu) | (fA3.y << 16); hv[3].y = (fA3.z & 0xFFFFu) | (fA3.w << 16);
            hv[3].z = (fB3.x & 0xFFFFu) | (fB3.y << 16); hv[3].w = (fB3.z & 0xFFFFu) | (fB3.w << 16);
            break;
          }
          __builtin_amdgcn_s_sleep(1);
        }
      } else {
        // ---- SLOW (proven r6): batched sc1 atomic poll of LLC
        const u64* hp = reinterpret_cast<const u64*>(hbuf + (u32)(t & 1) * 65536u + hrow_off);
        const u64 wpat = ((u64)tg) | ((u64)tg << 32);
        u64 raw[4][4];
        for (;;) {
#pragma unroll
          for (int kk = 0; kk < 4; ++kk) {
            const int base = (((wv << 2) | kk) << 4) | (oct << 2);
#pragma unroll
            for (int ee = 0; ee < 4; ++ee)
              raw[kk][ee] = __hip_atomic_load(hp + base + ee, __ATOMIC_RELAXED,
                                              __HIP_MEMORY_SCOPE_AGENT);
          }
          __builtin_amdgcn_sched_barrier(0);
          u64 chk = 0;
#pragma unroll
          for (int kk = 0; kk < 4; ++kk)
#pragma unroll
            for (int ee = 0; ee < 4; ++ee)
              chk |= (raw[kk][ee] ^ wpat) & 0xFFFF0000FFFF0000ull;
          if (__all(chk == 0)) break;
          __builtin_amdgcn_s_sleep(1);
        }
#pragma unroll
        for (int kk = 0; kk < 4; ++kk) {
          hv[kk].x = pkh(raw[kk][0]); hv[kk].y = pkh(raw[kk][1]);
          hv[kk].z = pkh(raw[kk][2]); hv[kk].w = pkh(raw[kk][3]);
        }
      }

#pragma unroll
      for (int kk = 0; kk < 4; ++kk) {
        const int kc = (wv << 2) | kk;
        f16x8 hf = __builtin_bit_cast(f16x8, hv[kk]);
        acc0 = __builtin_amdgcn_mfma_f32_16x16x32_f16(hf, __builtin_bit_cast(f16x8, sWh[(0 * 16 + kc) * 64 + lane]), acc0, 0, 0, 0);
        acc1 = __builtin_amdgcn_mfma_f32_16x16x32_f16(hf, __builtin_bit_cast(f16x8, sWh[(1 * 16 + kc) * 64 + lane]), acc1, 0, 0, 0);
        acc2 = __builtin_amdgcn_mfma_f32_16x16x32_f16(hf, __builtin_bit_cast(f16x8, sWh[(2 * 16 + kc) * 64 + lane]), acc2, 0, 0, 0);
        acc3 = __builtin_amdgcn_mfma_f32_16x16x32_f16(hf, __builtin_bit_cast(f16x8, sWh[(3 * 16 + kc) * 64 + lane]), acc3, 0, 0, 0);
      }
    }

    // ---- K-partial tiles -> pred, col-major: 4x ds_write_b128
    {
      const int cc = lane & 15;
      const int r0 = (lane >> 4) << 2;
      *reinterpret_cast<f32x4*>(&pred[wv * 4 + 0][PSTR * cc + r0]) = acc0;
      *reinterpret_cast<f32x4*>(&pred[wv * 4 + 1][PSTR * cc + r0]) = acc1;
      *reinterpret_cast<f32x4*>(&pred[wv * 4 + 2][PSTR * cc + r0]) = acc2;
      *reinterpret_cast<f32x4*>(&pred[wv * 4 + 3][PSTR * cc + r0]) = acc3;
    }
    asm volatile("s_waitcnt lgkmcnt(0)" ::: "memory");
    __builtin_amdgcn_s_barrier();
    __builtin_amdgcn_sched_barrier(0);

    // ---- gates; publish h(t+1) with embedded tag (flavored store)
    {
      float gi = bi, gf = bf_, gg = bg, go = bo;
#pragma unroll
      for (int w2 = 0; w2 < 4; ++w2) {
        gi += pred[w2 * 4 + 0][PSTR * hi_ + bt];
        gf += pred[w2 * 4 + 1][PSTR * hi_ + bt];
        gg += pred[w2 * 4 + 2][PSTR * hi_ + bt];
        go += pred[w2 * 4 + 3][PSTR * hi_ + bt];
      }
      const float si = 1.f / (1.f + __expf(-gi));
      const float sf = 1.f / (1.f + __expf(-gf));
      const float so = 1.f / (1.f + __expf(-go));
      c_reg = sf * c_reg + si * tanhf(gg);
      const float hv_ = so * tanhf(c_reg);
      const u32 word = ((u32)(t + 1) << 16) | (u32)f2h_bits(hv_);
      const u32 idx = (u32)((t + 1) & 1) * 65536u + (u32)gb * 512u + (u32)hidx;
      if (fastm)
        *reinterpret_cast<volatile u32*>(hbuf + idx) = word;  // dirty in own-XCD L2
      else
        __hip_atomic_store(hbuf + idx, word, __ATOMIC_RELAXED, __HIP_MEMORY_SCOPE_AGENT);
    }
    __builtin_amdgcn_s_barrier();   // pred reads vs next-step writes
    __builtin_amdgcn_sched_barrier(0);
  };

  for (int t = 0; t < S_LEN; t += 2) {
    step(t, xa, xb);
    step(t + 1, xb, xa);
  }

  // ---- Dense(1) on h(S): member 0 of each group; plane 0, tags == S_LEN
  if (m == 0) {
    const int btf = tid >> 4;
    const int part = tid & 15;
    const u32 tg = (u32)S_LEN << 16;
    float acc = 0.f;
    if (fastm) {
      const u32* ep = hbuf + (((u32)(g * GBAT + btf)) << 9) + (u32)part * 32u;
      u32x4 r0_, r1_, r2_, r3_, r4_, r5_, r6_, r7_;
      for (;;) {
        asm volatile("global_load_dwordx4 %0, %1, off sc0" : "=&v"(r0_) : "v"(ep));
        asm volatile("global_load_dwordx4 %0, %1, off offset:16 sc0" : "=&v"(r1_) : "v"(ep));
        asm volatile("global_load_dwordx4 %0, %1, off offset:32 sc0" : "=&v"(r2_) : "v"(ep));
        asm volatile("global_load_dwordx4 %0, %1, off offset:48 sc0" : "=&v"(r3_) : "v"(ep));
        asm volatile("global_load_dwordx4 %0, %1, off offset:64 sc0" : "=&v"(r4_) : "v"(ep));
        asm volatile("global_load_dwordx4 %0, %1, off offset:80 sc0" : "=&v"(r5_) : "v"(ep));
        asm volatile("global_load_dwordx4 %0, %1, off offset:96 sc0" : "=&v"(r6_) : "v"(ep));
        asm volatile("global_load_dwordx4 %0, %1, off offset:112 sc0" : "=&v"(r7_) : "v"(ep));
        asm volatile("s_waitcnt vmcnt(0)" ::: "memory");
        __builtin_amdgcn_sched_barrier(0);
        u32 bad = (r0_.x ^ tg) | (r0_.y ^ tg) | (r0_.z ^ tg) | (r0_.w ^ tg);
        bad |= (r1_.x ^ tg) | (r1_.y ^ tg) | (r1_.z ^ tg) | (r1_.w ^ tg);
        bad |= (r2_.x ^ tg) | (r2_.y ^ tg) | (r2_.z ^ tg) | (r2_.w ^ tg);
        bad |= (r3_.x ^ tg) | (r3_.y ^ tg) | (r3_.z ^ tg) | (r3_.w ^ tg);
        bad |= (r4_.x ^ tg) | (r4_.y ^ tg) | (r4_.z ^ tg) | (r4_.w ^ tg);
        bad |= (r5_.x ^ tg) | (r5_.y ^ tg) | (r5_.z ^ tg) | (r5_.w ^ tg);
        bad |= (r6_.x ^ tg) | (r6_.y ^ tg) | (r6_.z ^ tg) | (r6_.w ^ tg);
        bad |= (r7_.x ^ tg) | (r7_.y ^ tg) | (r7_.z ^ tg) | (r7_.w ^ tg);
        if (__all((bad & 0xFFFF0000u) == 0u)) break;
        __builtin_amdgcn_s_sleep(1);
      }
      const u32x4 rr[8] = {r0_, r1_, r2_, r3_, r4_, r5_, r6_, r7_};
#pragma unroll
      for (int j = 0; j < 8; ++j) {
        const int k = part * 32 + 4 * j;
        acc += h2f_bits((u16)(rr[j].x & 0xFFFFu)) * Wd[k] +
               h2f_bits((u16)(rr[j].y & 0xFFFFu)) * Wd[k + 1] +
               h2f_bits((u16)(rr[j].z & 0xFFFFu)) * Wd[k + 2] +
               h2f_bits((u16)(rr[j].w & 0xFFFFu)) * Wd[k + 3];
      }
    } else {
      const u64* hp = reinterpret_cast<const u64*>(hbuf + (((u32)(g * GBAT + btf)) << 9));
      const u64 wpat = ((u64)tg) | ((u64)tg << 32);
      u64 rawv[16];
      for (;;) {
#pragma unroll
        for (int j2 = 0; j2 < 16; ++j2)
          rawv[j2] = __hip_atomic_load(hp + part * 16 + j2, __ATOMIC_RELAXED,
                                       __HIP_MEMORY_SCOPE_AGENT);
        __builtin_amdgcn_sched_barrier(0);
        u64 chk = 0;
#pragma unroll
        for (int j2 = 0; j2 < 16; ++j2)
          chk |= (rawv[j2] ^ wpat) & 0xFFFF0000FFFF0000ull;
        if (__all(chk == 0)) break;
        __builtin_amdgcn_s_sleep(1);
      }
#pragma unroll
      for (int j2 = 0; j2 < 16; ++j2) {
        const int k = part * 32 + 2 * j2;
        acc += h2f_bits((u16)(rawv[j2] & 0xFFFFu)) * Wd[k] +
               h2f_bits((u16)((rawv[j2] >> 32) & 0xFFFFu)) * Wd[k + 1];
      }
    }
#pragma unroll
    for (int s = 1; s < 16; s <<= 1) acc += __shfl_xor(acc, s, 64);
    if (part == 0) out[g * GBAT + btf] = acc + bd[0];
  }
}

extern "C" void kernel_launch(void* const* d_in, const int* in_sizes, int n_in,
                              void* d_out, int out_size, void* d_ws, size_t ws_size,
                              hipStream_t stream) {
  const float* x = (const float*)d_in[0];
  const float* Wi = (const float*)d_in[1];
  const float* Wh = (const float*)d_in[2];
  const float* bv = (const float*)d_in[3];
  const float* Wd = (const float*)d_in[4];
  const float* bd = (const float*)d_in[5];
  float* out = (float*)d_out;

  // ws: [0,4MB) W frags | [4MB,4.5MB) hbuf | [4.5MB,+64B) roster
  char* ws = (char*)d_ws;
  uint4* wif4 = (uint4*)ws;
  u32* hbuf = (u32*)(ws + (4u << 20));
  u32* roster = (u32*)(ws + (4u << 20) + (512u << 10));

  hipLaunchKernelGGL(prep_frags, dim3(64), dim3(256), 0, stream, Wi, Wh, wif4, roster);

  const float* kx = x;
  const uint4* kw = wif4;
  u32* kh = hbuf;
  u32* kr = roster;
  const float* kbv = bv;
  const float* kwd = Wd;
  const float* kbd = bd;
  float* ko = out;
  void* args[] = {&kx, &kw, &kh, &kr, &kbv, &kwd, &kbd, &ko};
  (void)hipLaunchCooperativeKernel(reinterpret_cast<void*>(lstm_main), dim3(NG * NM),
                                   dim3(256), args, 0, stream);
}

// Round 17
// 3892.068 us; speedup vs baseline: 1.0147x; 1.0147x over previous
//
#include <hip/hip_runtime.h>

typedef unsigned int u32;
typedef unsigned short u16;
typedef unsigned long long u64;
typedef float f32x4 __attribute__((ext_vector_type(4)));
typedef _Float16 f16x8 __attribute__((ext_vector_type(8)));
typedef u32 u32x4 __attribute__((ext_vector_type(4)));

#define S_LEN 1024
#define NG 8      // groups = XCDs (dynamic mode) or bid&7 (fallback)
#define NM 32     // member blocks per group
#define GBAT 16   // batches per group
#define PSTR 20   // pred col stride (floats)

__device__ __forceinline__ u16 f2h_bits(float f) {
  _Float16 h = (_Float16)f;
  return __builtin_bit_cast(u16, h);
}
__device__ __forceinline__ float h2f_bits(u16 b) {
  return (float)__builtin_bit_cast(_Float16, b);
}
__device__ __forceinline__ u32 pk2(float a, float b) {
  return (u32)f2h_bits(a) | ((u32)f2h_bits(b) << 16);
}
__device__ __forceinline__ u32 pkh(u64 v) {
  return (u32)(v & 0xFFFFu) | (((u32)(v >> 32) & 0xFFFFu) << 16);
}

// Pre-arrange W into MFMA fragment-major order, fp16 (layout verified r2-r14);
// blk 0 zeroes the roster (16 words) -> graph-replay safe.
__global__ __launch_bounds__(256) void prep_frags(const float* __restrict__ Wi,
                                                  const float* __restrict__ Wh,
                                                  uint4* __restrict__ wf4,
                                                  u32* __restrict__ roster) {
  const int blk = blockIdx.x;               // 0..63
  if (blk == 0 && threadIdx.x < 16) roster[threadIdx.x] = 0;
  const int m = blk & 31;
  const float* __restrict__ W = (blk & 32) ? Wh : Wi;
  uint4* __restrict__ dst = wf4 + ((blk & 32) ? 131072 : 0) + m * 4096;
  for (int fi = threadIdx.x; fi < 4096; fi += 256) {
    const int lane = fi & 63;
    const int kc = (fi >> 6) & 15;
    const int q = fi >> 10;
    const int gq = lane >> 4, c = lane & 15;
    const int kb = kc * 32 + gq * 8;
    const int gcol = q * 512 + m * 16 + c;
    u32 wds[4];
#pragma unroll
    for (int pp = 0; pp < 4; ++pp) {
      u16 e0 = f2h_bits(W[(size_t)(kb + 2 * pp) * 2048 + gcol]);
      u16 e1 = f2h_bits(W[(size_t)(kb + 2 * pp + 1) * 2048 + gcol]);
      wds[pp] = (u32)e0 | ((u32)e1 << 16);
    }
    uint4 v; v.x = wds[0]; v.y = wds[1]; v.z = wds[2]; v.w = wds[3];
    dst[fi] = v;    // fi == (q*16+kc)*64+lane
  }
}

// Persistent LSTM, tagged-word protocol (word = (seq16<<16)|f16(h)).
// Final standing kernel = r11/r14 (passed twice, 3947/3949us, identical
// counters). Dynamic XCD grouping with uniform fallback to the proven
// static-group LLC sc1-atomic protocol. Structural ceiling note: 1024 serial
// steps x ~3.85us/step of chip-wide h-rendezvous; 7 sync variants spanned
// mechanism/route/volume/ordering within 9% of this period.
__global__ __launch_bounds__(256) void lstm_main(
    const float* __restrict__ x,
    const uint4* __restrict__ wif4,
    u32* __restrict__ hbuf,
    u32* __restrict__ roster,
    const float* __restrict__ bvec,
    const float* __restrict__ Wd,
    const float* __restrict__ bd,
    float* __restrict__ out) {
  __shared__ __align__(16) uint4 sWi[4096];
  __shared__ __align__(16) uint4 sWh[4096];
  __shared__ __align__(16) float pred[16][PSTR * 16];
  __shared__ u32 sMode, sG, sM;

  const int tid = threadIdx.x;
  const int lane = tid & 63;
  const int wv = tid >> 6;

  // ---- dynamic group formation (once)
  if (tid == 0) {
    u32 myxcc;
    asm volatile("s_getreg_b32 %0, hwreg(HW_REG_XCC_ID)" : "=s"(myxcc));
    const u32 x8 = myxcc & 7u;
    const u32 slot = __hip_atomic_fetch_add(roster + x8, 1u, __ATOMIC_RELAXED,
                                            __HIP_MEMORY_SCOPE_AGENT);
    __hip_atomic_fetch_add(roster + 8, 1u, __ATOMIC_RELAXED, __HIP_MEMORY_SCOPE_AGENT);
    while (__hip_atomic_load(roster + 8, __ATOMIC_RELAXED, __HIP_MEMORY_SCOPE_AGENT) < 256u)
      __builtin_amdgcn_s_sleep(1);
    u32 ok = (slot < 32u) ? 1u : 0u;
    for (int k = 0; k < 8; ++k)
      ok &= (__hip_atomic_load(roster + k, __ATOMIC_RELAXED,
                               __HIP_MEMORY_SCOPE_AGENT) == 32u) ? 1u : 0u;
    sMode = ok; sG = x8; sM = slot;
  }
  __syncthreads();
  const bool fastm = (sMode != 0u);
  const int g = fastm ? (int)sG : ((int)blockIdx.x & 7);
  const int m = fastm ? (int)sM : ((int)blockIdx.x >> 3);

  for (int i = tid; i < 4096; i += 256) {
    sWi[i] = wif4[m * 4096 + i];
    sWh[i] = wif4[131072 + m * 4096 + i];
  }

  const int bt = tid >> 4;          // batch within group (output row)
  const int hi_ = tid & 15;         // h-index within member slice (output col)
  const int gb = g * GBAT + bt;
  const int hidx = m * 16 + hi_;

  const float bi = bvec[hidx];
  const float bf_ = bvec[512 + hidx];
  const float bg = bvec[1024 + hidx];
  const float bo = bvec[1536 + hidx];
  float c_reg = 0.f;

  // per-lane A-fragment source coordinates (verified r2-r14)
  const int abt = lane & 15;        // batch row this lane supplies
  const int oct = lane >> 4;        // k-octet within kc
  const float* __restrict__ xrow = x + (size_t)(g * GBAT + abt) * (S_LEN * 512);
  const u32 hrow_off = ((u32)(g * GBAT + abt)) << 9;

  __syncthreads();   // weights ready

  float4 xa[8], xb[8];
#pragma unroll
  for (int kk = 0; kk < 4; ++kk) {
    const int k0 = ((wv << 2) | kk) * 32 + oct * 8;
    xa[2 * kk]     = *reinterpret_cast<const float4*>(xrow + k0);
    xa[2 * kk + 1] = *reinterpret_cast<const float4*>(xrow + k0 + 4);
  }

  auto step = [&](int t, float4* cur, float4* nxt) {
    // ---- issue x(t+1) prefetch
    {
      int tn = t + 1; tn = (tn < S_LEN) ? tn : (S_LEN - 1);
      const float* xr = xrow + (size_t)tn * 512;
#pragma unroll
      for (int kk = 0; kk < 4; ++kk) {
        const int k0 = ((wv << 2) | kk) * 32 + oct * 8;
        nxt[2 * kk]     = *reinterpret_cast<const float4*>(xr + k0);
        nxt[2 * kk + 1] = *reinterpret_cast<const float4*>(xr + k0 + 4);
      }
    }

    // ---- x(t) @ Wi from prefetched regs
    f32x4 acc0 = {0.f, 0.f, 0.f, 0.f}, acc1 = acc0, acc2 = acc0, acc3 = acc0;
#pragma unroll
    for (int kk = 0; kk < 4; ++kk) {
      const int kc = (wv << 2) | kk;
      uint4 av;
      av.x = pk2(cur[2 * kk].x, cur[2 * kk].y);
      av.y = pk2(cur[2 * kk].z, cur[2 * kk].w);
      av.z = pk2(cur[2 * kk + 1].x, cur[2 * kk + 1].y);
      av.w = pk2(cur[2 * kk + 1].z, cur[2 * kk + 1].w);
      f16x8 af = __builtin_bit_cast(f16x8, av);
      acc0 = __builtin_amdgcn_mfma_f32_16x16x32_f16(af, __builtin_bit_cast(f16x8, sWi[(0 * 16 + kc) * 64 + lane]), acc0, 0, 0, 0);
      acc1 = __builtin_amdgcn_mfma_f32_16x16x32_f16(af, __builtin_bit_cast(f16x8, sWi[(1 * 16 + kc) * 64 + lane]), acc1, 0, 0, 0);
      acc2 = __builtin_amdgcn_mfma_f32_16x16x32_f16(af, __builtin_bit_cast(f16x8, sWi[(2 * 16 + kc) * 64 + lane]), acc2, 0, 0, 0);
      acc3 = __builtin_amdgcn_mfma_f32_16x16x32_f16(af, __builtin_bit_cast(f16x8, sWi[(3 * 16 + kc) * 64 + lane]), acc3, 0, 0, 0);
    }

    if (t > 0) {
      const u32 tg = (u32)t << 16;
      uint4 hv[4];

      if (fastm) {
        // ---- FAST: poll own-XCD L2 with sc0 loads
        const u32* p2 = hbuf + (((u32)(t & 1)) << 16) + hrow_off +
                        ((u32)((wv << 7) | (oct << 3)));
        for (;;) {
          u32x4 fA0, fB0, fA1, fB1, fA2, fB2, fA3, fB3;
          asm volatile("global_load_dwordx4 %0, %1, off sc0" : "=&v"(fA0) : "v"(p2));
          asm volatile("global_load_dwordx4 %0, %1, off offset:16 sc0" : "=&v"(fB0) : "v"(p2));
          asm volatile("global_load_dwordx4 %0, %1, off offset:128 sc0" : "=&v"(fA1) : "v"(p2));
          asm volatile("global_load_dwordx4 %0, %1, off offset:144 sc0" : "=&v"(fB1) : "v"(p2));
          asm volatile("global_load_dwordx4 %0, %1, off offset:256 sc0" : "=&v"(fA2) : "v"(p2));
          asm volatile("global_load_dwordx4 %0, %1, off offset:272 sc0" : "=&v"(fB2) : "v"(p2));
          asm volatile("global_load_dwordx4 %0, %1, off offset:384 sc0" : "=&v"(fA3) : "v"(p2));
          asm volatile("global_load_dwordx4 %0, %1, off offset:400 sc0" : "=&v"(fB3) : "v"(p2));
          asm volatile("s_waitcnt vmcnt(0)" ::: "memory");
          __builtin_amdgcn_sched_barrier(0);
          u32 bad = (fA0.x ^ tg) | (fA0.y ^ tg) | (fA0.z ^ tg) | (fA0.w ^ tg);
          bad |= (fB0.x ^ tg) | (fB0.y ^ tg) | (fB0.z ^ tg) | (fB0.w ^ tg);
          bad |= (fA1.x ^ tg) | (fA1.y ^ tg) | (fA1.z ^ tg) | (fA1.w ^ tg);
          bad |= (fB1.x ^ tg) | (fB1.y ^ tg) | (fB1.z ^ tg) | (fB1.w ^ tg);
          bad |= (fA2.x ^ tg) | (fA2.y ^ tg) | (fA2.z ^ tg) | (fA2.w ^ tg);
          bad |= (fB2.x ^ tg) | (fB2.y ^ tg) | (fB2.z ^ tg) | (fB2.w ^ tg);
          bad |= (fA3.x ^ tg) | (fA3.y ^ tg) | (fA3.z ^ tg) | (fA3.w ^ tg);
          bad |= (fB3.x ^ tg) | (fB3.y ^ tg) | (fB3.z ^ tg) | (fB3.w ^ tg);
          if (__all((bad & 0xFFFF0000u) == 0u)) {
            hv[0].x = (fA0.x & 0xFFFFu) | (fA0.y << 16); hv[0].y = (fA0.z & 0xFFFFu) | (fA0.w << 16);
            hv[0].z = (fB0.x & 0xFFFFu) | (fB0.y << 16); hv[0].w = (fB0.z & 0xFFFFu) | (fB0.w << 16);
            hv[1].x = (fA1.x & 0xFFFFu) | (fA1.y << 16); hv[1].y = (fA1.z & 0xFFFFu) | (fA1.w << 16);
            hv[1].z = (fB1.x & 0xFFFFu) | (fB1.y << 16); hv[1].w = (fB1.z & 0xFFFFu) | (fB1.w << 16);
            hv[2].x = (fA2.x & 0xFFFFu) | (fA2.y << 16); hv[2].y = (fA2.z & 0xFFFFu) | (fA2.w << 16);
            hv[2].z = (fB2.x & 0xFFFFu) | (fB2.y << 16); hv[2].w = (fB2.z & 0xFFFFu) | (fB2.w << 16);
            hv[3].x = (fA3.x & 0xFFFFu) | (fA3.y << 16); hv[3].y = (fA3.z & 0xFFFFu) | (fA3.w << 16);
            hv[3].z = (fB3.x & 0xFFFFu) | (fB3.y << 16); hv[3].w = (fB3.z & 0xFFFFu) | (fB3.w << 16);
            break;
          }
          __builtin_amdgcn_s_sleep(1);
        }
      } else {
        // ---- SLOW (proven r6): batched sc1 atomic poll of LLC
        const u64* hp = reinterpret_cast<const u64*>(hbuf + (u32)(t & 1) * 65536u + hrow_off);
        const u64 wpat = ((u64)tg) | ((u64)tg << 32);
        u64 raw[4][4];
        for (;;) {
#pragma unroll
          for (int kk = 0; kk < 4; ++kk) {
            const int base = (((wv << 2) | kk) << 4) | (oct << 2);
#pragma unroll
            for (int ee = 0; ee < 4; ++ee)
              raw[kk][ee] = __hip_atomic_load(hp + base + ee, __ATOMIC_RELAXED,
                                              __HIP_MEMORY_SCOPE_AGENT);
          }
          __builtin_amdgcn_sched_barrier(0);
          u64 chk = 0;
#pragma unroll
          for (int kk = 0; kk < 4; ++kk)
#pragma unroll
            for (int ee = 0; ee < 4; ++ee)
              chk |= (raw[kk][ee] ^ wpat) & 0xFFFF0000FFFF0000ull;
          if (__all(chk == 0)) break;
          __builtin_amdgcn_s_sleep(1);
        }
#pragma unroll
        for (int kk = 0; kk < 4; ++kk) {
          hv[kk].x = pkh(raw[kk][0]); hv[kk].y = pkh(raw[kk][1]);
          hv[kk].z = pkh(raw[kk][2]); hv[kk].w = pkh(raw[kk][3]);
        }
      }

#pragma unroll
      for (int kk = 0; kk < 4; ++kk) {
        const int kc = (wv << 2) | kk;
        f16x8 hf = __builtin_bit_cast(f16x8, hv[kk]);
        acc0 = __builtin_amdgcn_mfma_f32_16x16x32_f16(hf, __builtin_bit_cast(f16x8, sWh[(0 * 16 + kc) * 64 + lane]), acc0, 0, 0, 0);
        acc1 = __builtin_amdgcn_mfma_f32_16x16x32_f16(hf, __builtin_bit_cast(f16x8, sWh[(1 * 16 + kc) * 64 + lane]), acc1, 0, 0, 0);
        acc2 = __builtin_amdgcn_mfma_f32_16x16x32_f16(hf, __builtin_bit_cast(f16x8, sWh[(2 * 16 + kc) * 64 + lane]), acc2, 0, 0, 0);
        acc3 = __builtin_amdgcn_mfma_f32_16x16x32_f16(hf, __builtin_bit_cast(f16x8, sWh[(3 * 16 + kc) * 64 + lane]), acc3, 0, 0, 0);
      }
    }

    // ---- K-partial tiles -> pred, col-major: 4x ds_write_b128
    {
      const int cc = lane & 15;
      const int r0 = (lane >> 4) << 2;
      *reinterpret_cast<f32x4*>(&pred[wv * 4 + 0][PSTR * cc + r0]) = acc0;
      *reinterpret_cast<f32x4*>(&pred[wv * 4 + 1][PSTR * cc + r0]) = acc1;
      *reinterpret_cast<f32x4*>(&pred[wv * 4 + 2][PSTR * cc + r0]) = acc2;
      *reinterpret_cast<f32x4*>(&pred[wv * 4 + 3][PSTR * cc + r0]) = acc3;
    }
    asm volatile("s_waitcnt lgkmcnt(0)" ::: "memory");
    __builtin_amdgcn_s_barrier();
    __builtin_amdgcn_sched_barrier(0);

    // ---- gates; publish h(t+1) with embedded tag (flavored store)
    {
      float gi = bi, gf = bf_, gg = bg, go = bo;
#pragma unroll
      for (int w2 = 0; w2 < 4; ++w2) {
        gi += pred[w2 * 4 + 0][PSTR * hi_ + bt];
        gf += pred[w2 * 4 + 1][PSTR * hi_ + bt];
        gg += pred[w2 * 4 + 2][PSTR * hi_ + bt];
        go += pred[w2 * 4 + 3][PSTR * hi_ + bt];
      }
      const float si = 1.f / (1.f + __expf(-gi));
      const float sf = 1.f / (1.f + __expf(-gf));
      const float so = 1.f / (1.f + __expf(-go));
      c_reg = sf * c_reg + si * tanhf(gg);
      const float hv_ = so * tanhf(c_reg);
      const u32 word = ((u32)(t + 1) << 16) | (u32)f2h_bits(hv_);
      const u32 idx = (u32)((t + 1) & 1) * 65536u + (u32)gb * 512u + (u32)hidx;
      if (fastm)
        *reinterpret_cast<volatile u32*>(hbuf + idx) = word;  // dirty in own-XCD L2
      else
        __hip_atomic_store(hbuf + idx, word, __ATOMIC_RELAXED, __HIP_MEMORY_SCOPE_AGENT);
    }
    __builtin_amdgcn_s_barrier();   // pred reads vs next-step writes
    __builtin_amdgcn_sched_barrier(0);
  };

  for (int t = 0; t < S_LEN; t += 2) {
    step(t, xa, xb);
    step(t + 1, xb, xa);
  }

  // ---- Dense(1) on h(S): member 0 of each group; plane 0, tags == S_LEN
  if (m == 0) {
    const int btf = tid >> 4;
    const int part = tid & 15;
    const u32 tg = (u32)S_LEN << 16;
    float acc = 0.f;
    if (fastm) {
      const u32* ep = hbuf + (((u32)(g * GBAT + btf)) << 9) + (u32)part * 32u;
      u32x4 r0_, r1_, r2_, r3_, r4_, r5_, r6_, r7_;
      for (;;) {
        asm volatile("global_load_dwordx4 %0, %1, off sc0" : "=&v"(r0_) : "v"(ep));
        asm volatile("global_load_dwordx4 %0, %1, off offset:16 sc0" : "=&v"(r1_) : "v"(ep));
        asm volatile("global_load_dwordx4 %0, %1, off offset:32 sc0" : "=&v"(r2_) : "v"(ep));
        asm volatile("global_load_dwordx4 %0, %1, off offset:48 sc0" : "=&v"(r3_) : "v"(ep));
        asm volatile("global_load_dwordx4 %0, %1, off offset:64 sc0" : "=&v"(r4_) : "v"(ep));
        asm volatile("global_load_dwordx4 %0, %1, off offset:80 sc0" : "=&v"(r5_) : "v"(ep));
        asm volatile("global_load_dwordx4 %0, %1, off offset:96 sc0" : "=&v"(r6_) : "v"(ep));
        asm volatile("global_load_dwordx4 %0, %1, off offset:112 sc0" : "=&v"(r7_) : "v"(ep));
        asm volatile("s_waitcnt vmcnt(0)" ::: "memory");
        __builtin_amdgcn_sched_barrier(0);
        u32 bad = (r0_.x ^ tg) | (r0_.y ^ tg) | (r0_.z ^ tg) | (r0_.w ^ tg);
        bad |= (r1_.x ^ tg) | (r1_.y ^ tg) | (r1_.z ^ tg) | (r1_.w ^ tg);
        bad |= (r2_.x ^ tg) | (r2_.y ^ tg) | (r2_.z ^ tg) | (r2_.w ^ tg);
        bad |= (r3_.x ^ tg) | (r3_.y ^ tg) | (r3_.z ^ tg) | (r3_.w ^ tg);
        bad |= (r4_.x ^ tg) | (r4_.y ^ tg) | (r4_.z ^ tg) | (r4_.w ^ tg);
        bad |= (r5_.x ^ tg) | (r5_.y ^ tg) | (r5_.z ^ tg) | (r5_.w ^ tg);
        bad |= (r6_.x ^ tg) | (r6_.y ^ tg) | (r6_.z ^ tg) | (r6_.w ^ tg);
        bad |= (r7_.x ^ tg) | (r7_.y ^ tg) | (r7_.z ^ tg) | (r7_.w ^ tg);
        if (__all((bad & 0xFFFF0000u) == 0u)) break;
        __builtin_amdgcn_s_sleep(1);
      }
      const u32x4 rr[8] = {r0_, r1_, r2_, r3_, r4_, r5_, r6_, r7_};
#pragma unroll
      for (int j = 0; j < 8; ++j) {
        const int k = part * 32 + 4 * j;
        acc += h2f_bits((u16)(rr[j].x & 0xFFFFu)) * Wd[k] +
               h2f_bits((u16)(rr[j].y & 0xFFFFu)) * Wd[k + 1] +
               h2f_bits((u16)(rr[j].z & 0xFFFFu)) * Wd[k + 2] +
               h2f_bits((u16)(rr[j].w & 0xFFFFu)) * Wd[k + 3];
      }
    } else {
      const u64* hp = reinterpret_cast<const u64*>(hbuf + (((u32)(g * GBAT + btf)) << 9));
      const u64 wpat = ((u64)tg) | ((u64)tg << 32);
      u64 rawv[16];
      for (;;) {
#pragma unroll
        for (int j2 = 0; j2 < 16; ++j2)
          rawv[j2] = __hip_atomic_load(hp + part * 16 + j2, __ATOMIC_RELAXED,
                                       __HIP_MEMORY_SCOPE_AGENT);
        __builtin_amdgcn_sched_barrier(0);
        u64 chk = 0;
#pragma unroll
        for (int j2 = 0; j2 < 16; ++j2)
          chk |= (rawv[j2] ^ wpat) & 0xFFFF0000FFFF0000ull;
        if (__all(chk == 0)) break;
        __builtin_amdgcn_s_sleep(1);
      }
#pragma unroll
      for (int j2 = 0; j2 < 16; ++j2) {
        const int k = part * 32 + 2 * j2;
        acc += h2f_bits((u16)(rawv[j2] & 0xFFFFu)) * Wd[k] +
               h2f_bits((u16)((rawv[j2] >> 32) & 0xFFFFu)) * Wd[k + 1];
      }
    }
#pragma unroll
    for (int s = 1; s < 16; s <<= 1) acc += __shfl_xor(acc, s, 64);
    if (part == 0) out[g * GBAT + btf] = acc + bd[0];
  }
}

extern "C" void kernel_launch(void* const* d_in, const int* in_sizes, int n_in,
                              void* d_out, int out_size, void* d_ws, size_t ws_size,
                              hipStream_t stream) {
  const float* x = (const float*)d_in[0];
  const float* Wi = (const float*)d_in[1];
  const float* Wh = (const float*)d_in[2];
  const float* bv = (const float*)d_in[3];
  const float* Wd = (const float*)d_in[4];
  const float* bd = (const float*)d_in[5];
  float* out = (float*)d_out;

  // ws: [0,4MB) W frags | [4MB,4.5MB) hbuf | [4.5MB,+64B) roster
  char* ws = (char*)d_ws;
  uint4* wif4 = (uint4*)ws;
  u32* hbuf = (u32*)(ws + (4u << 20));
  u32* roster = (u32*)(ws + (4u << 20) + (512u << 10));

  hipLaunchKernelGGL(prep_frags, dim3(64), dim3(256), 0, stream, Wi, Wh, wif4, roster);

  const float* kx = x;
  const uint4* kw = wif4;
  u32* kh = hbuf;
  u32* kr = roster;
  const float* kbv = bv;
  const float* kwd = Wd;
  const float* kbd = bd;
  float* ko = out;
  void* args[] = {&kx, &kw, &kh, &kr, &kbv, &kwd, &kbd, &ko};
  (void)hipLaunchCooperativeKernel(reinterpret_cast<void*>(lstm_main), dim3(NG * NM),
                                   dim3(256), args, 0, stream);
}